// Round 2
// baseline (1066.045 us; speedup 1.0000x reference)
//
#include <hip/hip_runtime.h>
#include <math.h>

#define NROWS 8192
#define NDET  4096

// ---------------- workspace layout (float element offsets) ----------------
// idx  [8192][8]  int32 @ 0         (65536)
// sgn  [8192][8]  float @ 65536     (65536)
// pn   [8192][64] float @ 131072    (524288)   pointnet max-pooled features
// agg  [8192][128]float @ 655360    (1048576)  aggregated features (reused, stride F)
// h1   [8192][64] float @ 1703936   (524288)
// h2   [8192][64] float @ 2228224   (524288)
static constexpr int OFF_SGN = 65536;
static constexpr int OFF_PN  = 131072;
static constexpr int OFF_AGG = 655360;
static constexpr int OFF_H1  = 1703936;
static constexpr int OFF_H2  = 2228224;

// ---- sparse extraction: one block per row, scan the half that can hold neighbors ----
__global__ void k_extract(const float* __restrict__ nodeA, const float* __restrict__ edgeA,
                          int* __restrict__ idx, float* __restrict__ sgn)
{
    int row = blockIdx.x, t = threadIdx.x;
    const float* src; int col0;
    if (row < NDET) { src = nodeA + (size_t)row * NROWS + NDET; col0 = NDET; }
    else            { src = edgeA + (size_t)row * NROWS;        col0 = 0;    }
    __shared__ int scnt;
    if (t == 0) scnt = 0;
    __syncthreads();
    const float4* s4 = (const float4*)src;
    #pragma unroll
    for (int it = 0; it < 4; ++it) {
        float4 v = s4[t + it * 256];
        int cb = col0 + (t + it * 256) * 4;
        if (v.x != 0.f) { int p = atomicAdd(&scnt, 1); idx[row * 8 + p] = cb;     sgn[row * 8 + p] = v.x; }
        if (v.y != 0.f) { int p = atomicAdd(&scnt, 1); idx[row * 8 + p] = cb + 1; sgn[row * 8 + p] = v.y; }
        if (v.z != 0.f) { int p = atomicAdd(&scnt, 1); idx[row * 8 + p] = cb + 2; sgn[row * 8 + p] = v.z; }
        if (v.w != 0.f) { int p = atomicAdd(&scnt, 1); idx[row * 8 + p] = cb + 3; sgn[row * 8 + p] = v.w; }
    }
    __syncthreads();
    for (int p = scnt + t; p < 8; p += 256) { idx[row * 8 + p] = 0; sgn[row * 8 + p] = 0.f; }
}

// ---- pointnet (fold + conv stack + max over 5 points), thread = (row, 4 out channels) ----
// grid dim3(128,4), block 256: lane=row (coalesced), tid>>6 + blockIdx.y pick the f-range.
__global__ void k_pointnet(const float* __restrict__ x,
                           const float* __restrict__ w1, const float* __restrict__ b1,
                           const float* __restrict__ g1, const float* __restrict__ be1,
                           const float* __restrict__ m1, const float* __restrict__ v1,
                           const float* __restrict__ w2, const float* __restrict__ b2,
                           const float* __restrict__ g2, const float* __restrict__ be2,
                           const float* __restrict__ m2, const float* __restrict__ v2,
                           const float* __restrict__ w3, const float* __restrict__ b3,
                           const float* __restrict__ g3, const float* __restrict__ be3,
                           const float* __restrict__ m3, const float* __restrict__ v3,
                           float* __restrict__ pn)
{
    // folded weights: fw1[3][16]@0, fb1@48, fw2[16][32]@64, fb2@576, fw3[32][64]@608, fb3@2656
    __shared__ float fw[2720];
    int t = threadIdx.x;
    for (int i = t; i < 48; i += 256)  { int d = i & 15; fw[i]       = w1[i] * g1[d] * rsqrtf(v1[d] + 1e-5f); }
    for (int i = t; i < 16; i += 256)  {                 fw[48 + i]  = (b1[i] - m1[i]) * g1[i] * rsqrtf(v1[i] + 1e-5f) + be1[i]; }
    for (int i = t; i < 512; i += 256) { int d = i & 31; fw[64 + i]  = w2[i] * g2[d] * rsqrtf(v2[d] + 1e-5f); }
    for (int i = t; i < 32; i += 256)  {                 fw[576 + i] = (b2[i] - m2[i]) * g2[i] * rsqrtf(v2[i] + 1e-5f) + be2[i]; }
    for (int i = t; i < 2048; i += 256){ int d = i & 63; fw[608 + i] = w3[i] * g3[d] * rsqrtf(v3[d] + 1e-5f); }
    for (int i = t; i < 64; i += 256)  {                 fw[2656 + i]= (b3[i] - m3[i]) * g3[i] * rsqrtf(v3[i] + 1e-5f) + be3[i]; }
    __syncthreads();

    int lane = t & 63, fsub = t >> 6;
    int row  = blockIdx.x * 64 + lane;
    int f0   = (blockIdx.y * 4 + fsub) * 4;   // 4 contiguous output channels

    float vmax[4] = {-3.0e38f, -3.0e38f, -3.0e38f, -3.0e38f};
    for (int p = 0; p < 5; ++p) {
        float a0 = x[(size_t)row * 74 + 64 + p];
        float a1 = x[(size_t)row * 74 + 69 + p];
        float h1[16];
        #pragma unroll
        for (int d = 0; d < 16; ++d)
            h1[d] = fmaxf(0.f, a0 * fw[d] + a1 * fw[16 + d] + fw[48 + d]);
        float h2[32];
        #pragma unroll
        for (int e = 0; e < 32; ++e) {
            float s = fw[576 + e];
            #pragma unroll
            for (int d = 0; d < 16; ++d) s += h1[d] * fw[64 + d * 32 + e];
            h2[e] = fmaxf(0.f, s);
        }
        #pragma unroll
        for (int ff = 0; ff < 4; ++ff) {
            float s = fw[2656 + f0 + ff];
            #pragma unroll
            for (int e = 0; e < 32; ++e) s += h2[e] * fw[608 + e * 64 + f0 + ff];
            vmax[ff] = fmaxf(vmax[ff], s);
        }
    }
    float4 o; o.x = vmax[0]; o.y = vmax[1]; o.z = vmax[2]; o.w = vmax[3];
    *(float4*)&pn[(size_t)row * 64 + f0] = o;
}

// ---- layer-1 aggregation: wave per row, full-line coalesced neighbor reads ----
// agg[row][0:64] = x-part, agg[row][64:128] = pn-part
__global__ void k_gather1(const float* __restrict__ x, const float* __restrict__ pn,
                          const int* __restrict__ idx, const float* __restrict__ sgn,
                          float* __restrict__ agg)
{
    int lane = threadIdx.x & 63;
    int row  = blockIdx.x * 4 + (threadIdx.x >> 6);
    float acc0 = x[(size_t)row * 74 + lane];
    float acc1 = pn[(size_t)row * 64 + lane];
    #pragma unroll
    for (int j = 0; j < 8; ++j) {
        int nb   = idx[row * 8 + j];
        float sg = sgn[row * 8 + j];
        acc0 += sg * x[(size_t)nb * 74 + lane];
        acc1 += sg * pn[(size_t)nb * 64 + lane];
    }
    agg[(size_t)row * 128 + lane]      = acc0;
    agg[(size_t)row * 128 + 64 + lane] = acc1;
}

// ---- generic aggregation for F=64 activations ----
__global__ void k_gather2(const float* __restrict__ h, const int* __restrict__ idx,
                          const float* __restrict__ sgn, float* __restrict__ agg)
{
    int lane = threadIdx.x & 63;
    int row  = blockIdx.x * 4 + (threadIdx.x >> 6);
    float acc = h[(size_t)row * 64 + lane];
    #pragma unroll
    for (int j = 0; j < 8; ++j) {
        int nb   = idx[row * 8 + j];
        float sg = sgn[row * 8 + j];
        acc += sg * h[(size_t)nb * 64 + lane];
    }
    agg[(size_t)row * 64 + lane] = acc;
}

// ---- layer 1 GEMM: [x | pn | agg128] . W[256][64], thread = (row, 4 cols) ----
__global__ void k_gemm1(const float* __restrict__ x, const float* __restrict__ pn,
                        const float* __restrict__ agg,
                        const float* __restrict__ wn, const float* __restrict__ we,
                        const float* __restrict__ bn, const float* __restrict__ be,
                        float* __restrict__ out)
{
    int r_l = threadIdx.x >> 2, cg = threadIdx.x & 3;
    int row = blockIdx.x * 64 + r_l;
    int c0  = blockIdx.y * 16 + cg * 4;
    bool isnode = blockIdx.x < 64;             // 64-row blocks: block-uniform
    const float* W = isnode ? wn : we;
    const float* B = isnode ? bn : be;
    float acc[4] = {B[c0], B[c0 + 1], B[c0 + 2], B[c0 + 3]};

    const float2* x2 = (const float2*)(x + (size_t)row * 74);   // 74 floats: float2-aligned
    #pragma unroll
    for (int kg = 0; kg < 32; ++kg) {
        float2 v = x2[kg];
        float4 wv0 = *(const float4*)&W[(kg * 2) * 64 + c0];
        float4 wv1 = *(const float4*)&W[(kg * 2 + 1) * 64 + c0];
        acc[0] += v.x * wv0.x + v.y * wv1.x;
        acc[1] += v.x * wv0.y + v.y * wv1.y;
        acc[2] += v.x * wv0.z + v.y * wv1.z;
        acc[3] += v.x * wv0.w + v.y * wv1.w;
    }
    const float4* p4 = (const float4*)(pn + (size_t)row * 64);
    #pragma unroll
    for (int kg = 0; kg < 16; ++kg) {
        float4 v = p4[kg];
        const float* vv = &v.x;
        #pragma unroll
        for (int kk = 0; kk < 4; ++kk) {
            float4 wv = *(const float4*)&W[(64 + kg * 4 + kk) * 64 + c0];
            acc[0] += vv[kk] * wv.x; acc[1] += vv[kk] * wv.y;
            acc[2] += vv[kk] * wv.z; acc[3] += vv[kk] * wv.w;
        }
    }
    const float4* a4 = (const float4*)(agg + (size_t)row * 128);
    #pragma unroll
    for (int kg = 0; kg < 32; ++kg) {
        float4 v = a4[kg];
        const float* vv = &v.x;
        #pragma unroll
        for (int kk = 0; kk < 4; ++kk) {
            float4 wv = *(const float4*)&W[(128 + kg * 4 + kk) * 64 + c0];
            acc[0] += vv[kk] * wv.x; acc[1] += vv[kk] * wv.y;
            acc[2] += vv[kk] * wv.z; acc[3] += vv[kk] * wv.w;
        }
    }
    float4 o;
    o.x = fmaxf(acc[0], 0.f); o.y = fmaxf(acc[1], 0.f);
    o.z = fmaxf(acc[2], 0.f); o.w = fmaxf(acc[3], 0.f);
    *(float4*)&out[(size_t)row * 64 + c0] = o;
}

// ---- layer 2 GEMM: [h1 | agg64] . W[128][64] ----
__global__ void k_gemm2(const float* __restrict__ h, const float* __restrict__ agg,
                        const float* __restrict__ wn, const float* __restrict__ we,
                        const float* __restrict__ bn, const float* __restrict__ be,
                        float* __restrict__ out)
{
    int r_l = threadIdx.x >> 2, cg = threadIdx.x & 3;
    int row = blockIdx.x * 64 + r_l;
    int c0  = blockIdx.y * 16 + cg * 4;
    bool isnode = blockIdx.x < 64;
    const float* W = isnode ? wn : we;
    const float* B = isnode ? bn : be;
    float acc[4] = {B[c0], B[c0 + 1], B[c0 + 2], B[c0 + 3]};

    const float4* h4 = (const float4*)(h + (size_t)row * 64);
    const float4* a4 = (const float4*)(agg + (size_t)row * 64);
    #pragma unroll
    for (int kg = 0; kg < 16; ++kg) {
        float4 v = h4[kg];
        const float* vv = &v.x;
        #pragma unroll
        for (int kk = 0; kk < 4; ++kk) {
            float4 wv = *(const float4*)&W[(kg * 4 + kk) * 64 + c0];
            acc[0] += vv[kk] * wv.x; acc[1] += vv[kk] * wv.y;
            acc[2] += vv[kk] * wv.z; acc[3] += vv[kk] * wv.w;
        }
    }
    #pragma unroll
    for (int kg = 0; kg < 16; ++kg) {
        float4 v = a4[kg];
        const float* vv = &v.x;
        #pragma unroll
        for (int kk = 0; kk < 4; ++kk) {
            float4 wv = *(const float4*)&W[(64 + kg * 4 + kk) * 64 + c0];
            acc[0] += vv[kk] * wv.x; acc[1] += vv[kk] * wv.y;
            acc[2] += vv[kk] * wv.z; acc[3] += vv[kk] * wv.w;
        }
    }
    float4 o;
    o.x = fmaxf(acc[0], 0.f); o.y = fmaxf(acc[1], 0.f);
    o.z = fmaxf(acc[2], 0.f); o.w = fmaxf(acc[3], 0.f);
    *(float4*)&out[(size_t)row * 64 + c0] = o;
}

// ---- layer 3 fused: gather + 128->1 dot + sigmoid, wave per row ----
__global__ void k_gc3(const float* __restrict__ h2, const int* __restrict__ idx,
                      const float* __restrict__ sgn,
                      const float* __restrict__ wn, const float* __restrict__ we,
                      const float* __restrict__ bn, const float* __restrict__ be,
                      float* __restrict__ out)
{
    int lane = threadIdx.x & 63;
    int row  = blockIdx.x * 4 + (threadIdx.x >> 6);
    float own = h2[(size_t)row * 64 + lane];
    float agg = own;
    #pragma unroll
    for (int j = 0; j < 8; ++j) {
        int nb   = idx[row * 8 + j];
        float sg = sgn[row * 8 + j];
        agg += sg * h2[(size_t)nb * 64 + lane];
    }
    bool isnode = row < NDET;                  // wave-uniform (rows per wave aligned)
    const float* w = isnode ? wn : we;
    float bias = isnode ? bn[0] : be[0];
    float acc = own * w[lane] + agg * w[64 + lane];
    #pragma unroll
    for (int off = 32; off > 0; off >>= 1)
        acc += __shfl_xor(acc, off, 64);
    if (lane == 0)
        out[row] = 1.f / (1.f + expf(-(acc + bias)));
}

extern "C" void kernel_launch(void* const* d_in, const int* in_sizes, int n_in,
                              void* d_out, int out_size, void* d_ws, size_t ws_size,
                              hipStream_t stream)
{
    const float* x     = (const float*)d_in[0];
    const float* nodeA = (const float*)d_in[1];
    const float* edgeA = (const float*)d_in[2];
    const float* pw1 = (const float*)d_in[3];  const float* pb1 = (const float*)d_in[4];
    const float* pg1 = (const float*)d_in[5];  const float* pe1 = (const float*)d_in[6];
    const float* pm1 = (const float*)d_in[7];  const float* pv1 = (const float*)d_in[8];
    const float* pw2 = (const float*)d_in[9];  const float* pb2 = (const float*)d_in[10];
    const float* pg2 = (const float*)d_in[11]; const float* pe2 = (const float*)d_in[12];
    const float* pm2 = (const float*)d_in[13]; const float* pv2 = (const float*)d_in[14];
    const float* pw3 = (const float*)d_in[15]; const float* pb3 = (const float*)d_in[16];
    const float* pg3 = (const float*)d_in[17]; const float* pe3 = (const float*)d_in[18];
    const float* pm3 = (const float*)d_in[19]; const float* pv3 = (const float*)d_in[20];
    const float* g1wn = (const float*)d_in[21]; const float* g1we = (const float*)d_in[22];
    const float* g1bn = (const float*)d_in[23]; const float* g1be = (const float*)d_in[24];
    const float* g2wn = (const float*)d_in[25]; const float* g2we = (const float*)d_in[26];
    const float* g2bn = (const float*)d_in[27]; const float* g2be = (const float*)d_in[28];
    const float* g3wn = (const float*)d_in[29]; const float* g3we = (const float*)d_in[30];
    const float* g3bn = (const float*)d_in[31]; const float* g3be = (const float*)d_in[32];

    float* ws  = (float*)d_ws;
    int*   idx = (int*)ws;
    float* sgn = ws + OFF_SGN;
    float* pn  = ws + OFF_PN;
    float* agg = ws + OFF_AGG;
    float* h1  = ws + OFF_H1;
    float* h2  = ws + OFF_H2;
    float* out = (float*)d_out;

    k_extract<<<NROWS, 256, 0, stream>>>(nodeA, edgeA, idx, sgn);
    k_pointnet<<<dim3(128, 4), 256, 0, stream>>>(x,
        pw1, pb1, pg1, pe1, pm1, pv1,
        pw2, pb2, pg2, pe2, pm2, pv2,
        pw3, pb3, pg3, pe3, pm3, pv3, pn);
    k_gather1<<<2048, 256, 0, stream>>>(x, pn, idx, sgn, agg);
    k_gemm1<<<dim3(128, 4), 256, 0, stream>>>(x, pn, agg, g1wn, g1we, g1bn, g1be, h1);
    k_gather2<<<2048, 256, 0, stream>>>(h1, idx, sgn, agg);
    k_gemm2<<<dim3(128, 4), 256, 0, stream>>>(h1, agg, g2wn, g2we, g2bn, g2be, h2);
    k_gc3<<<2048, 256, 0, stream>>>(h2, idx, sgn, g3wn, g3we, g3bn, g3be, out);
}

// Round 3
// 974.625 us; speedup vs baseline: 1.0938x; 1.0938x over previous
//
#include <hip/hip_runtime.h>
#include <math.h>

#define NROWS 8192
#define NDET  4096

// ---------------- workspace layout (float element offsets) ----------------
static constexpr int OFF_SGN = 65536;
static constexpr int OFF_PN  = 131072;
static constexpr int OFF_AGG = 655360;
static constexpr int OFF_H1  = 1703936;
static constexpr int OFF_H2  = 2228224;

// ---- sparse extraction: one block per row, scan the half that can hold neighbors ----
__global__ __launch_bounds__(256) void k_extract(
    const float* __restrict__ nodeA, const float* __restrict__ edgeA,
    int* __restrict__ idx, float* __restrict__ sgn)
{
    int row = blockIdx.x, t = threadIdx.x;
    const float* src; int col0;
    if (row < NDET) { src = nodeA + (size_t)row * NROWS + NDET; col0 = NDET; }
    else            { src = edgeA + (size_t)row * NROWS;        col0 = 0;    }
    __shared__ int scnt;
    if (t == 0) scnt = 0;
    __syncthreads();
    const float4* s4 = (const float4*)src;
    #pragma unroll
    for (int it = 0; it < 4; ++it) {
        float4 v = s4[t + it * 256];
        int cb = col0 + (t + it * 256) * 4;
        if (v.x != 0.f) { int p = atomicAdd(&scnt, 1); idx[row * 8 + p] = cb;     sgn[row * 8 + p] = v.x; }
        if (v.y != 0.f) { int p = atomicAdd(&scnt, 1); idx[row * 8 + p] = cb + 1; sgn[row * 8 + p] = v.y; }
        if (v.z != 0.f) { int p = atomicAdd(&scnt, 1); idx[row * 8 + p] = cb + 2; sgn[row * 8 + p] = v.z; }
        if (v.w != 0.f) { int p = atomicAdd(&scnt, 1); idx[row * 8 + p] = cb + 3; sgn[row * 8 + p] = v.w; }
    }
    __syncthreads();
    for (int p = scnt + t; p < 8; p += 256) { idx[row * 8 + p] = 0; sgn[row * 8 + p] = 0.f; }
}

// ---- pointnet (fold + conv stack + max over 5 points), thread = (row, 4 out channels) ----
// __launch_bounds__(256,2): VGPR cap 256 so h1[16]/h2[32] stay in registers (r2: VGPR=64 -> scratch spill, 1.4 GB HBM traffic)
__global__ __launch_bounds__(256, 2) void k_pointnet(
    const float* __restrict__ x,
    const float* __restrict__ w1, const float* __restrict__ b1,
    const float* __restrict__ g1, const float* __restrict__ be1,
    const float* __restrict__ m1, const float* __restrict__ v1,
    const float* __restrict__ w2, const float* __restrict__ b2,
    const float* __restrict__ g2, const float* __restrict__ be2,
    const float* __restrict__ m2, const float* __restrict__ v2,
    const float* __restrict__ w3, const float* __restrict__ b3,
    const float* __restrict__ g3, const float* __restrict__ be3,
    const float* __restrict__ m3, const float* __restrict__ v3,
    float* __restrict__ pn)
{
    // folded weights: fw1[3][16]@0, fb1@48, fw2[16][32]@64, fb2@576, fw3[32][64]@608, fb3@2656
    __shared__ float fw[2720];
    int t = threadIdx.x;
    for (int i = t; i < 48; i += 256)  { int d = i & 15; fw[i]       = w1[i] * g1[d] * rsqrtf(v1[d] + 1e-5f); }
    for (int i = t; i < 16; i += 256)  {                 fw[48 + i]  = (b1[i] - m1[i]) * g1[i] * rsqrtf(v1[i] + 1e-5f) + be1[i]; }
    for (int i = t; i < 512; i += 256) { int d = i & 31; fw[64 + i]  = w2[i] * g2[d] * rsqrtf(v2[d] + 1e-5f); }
    for (int i = t; i < 32; i += 256)  {                 fw[576 + i] = (b2[i] - m2[i]) * g2[i] * rsqrtf(v2[i] + 1e-5f) + be2[i]; }
    for (int i = t; i < 2048; i += 256){ int d = i & 63; fw[608 + i] = w3[i] * g3[d] * rsqrtf(v3[d] + 1e-5f); }
    for (int i = t; i < 64; i += 256)  {                 fw[2656 + i]= (b3[i] - m3[i]) * g3[i] * rsqrtf(v3[i] + 1e-5f) + be3[i]; }
    __syncthreads();

    int lane = t & 63, fsub = t >> 6;
    int row  = blockIdx.x * 64 + lane;
    int f0   = (blockIdx.y * 4 + fsub) * 4;   // 4 contiguous output channels

    float vmax[4] = {-3.0e38f, -3.0e38f, -3.0e38f, -3.0e38f};
    for (int p = 0; p < 5; ++p) {
        float a0 = x[(size_t)row * 74 + 64 + p];
        float a1 = x[(size_t)row * 74 + 69 + p];
        float h1[16];
        #pragma unroll
        for (int d = 0; d < 16; ++d)
            h1[d] = fmaxf(0.f, a0 * fw[d] + a1 * fw[16 + d] + fw[48 + d]);
        float h2[32];
        #pragma unroll
        for (int e = 0; e < 32; ++e) {
            float s = fw[576 + e];
            #pragma unroll
            for (int d = 0; d < 16; ++d) s += h1[d] * fw[64 + d * 32 + e];
            h2[e] = fmaxf(0.f, s);
        }
        #pragma unroll
        for (int ff = 0; ff < 4; ++ff) {
            float s = fw[2656 + f0 + ff];
            #pragma unroll
            for (int e = 0; e < 32; ++e) s += h2[e] * fw[608 + e * 64 + f0 + ff];
            vmax[ff] = fmaxf(vmax[ff], s);
        }
    }
    float4 o; o.x = vmax[0]; o.y = vmax[1]; o.z = vmax[2]; o.w = vmax[3];
    *(float4*)&pn[(size_t)row * 64 + f0] = o;
}

// ---- layer-1 aggregation: wave per row, full-line coalesced neighbor reads ----
__global__ __launch_bounds__(256) void k_gather1(
    const float* __restrict__ x, const float* __restrict__ pn,
    const int* __restrict__ idx, const float* __restrict__ sgn,
    float* __restrict__ agg)
{
    int lane = threadIdx.x & 63;
    int row  = blockIdx.x * 4 + (threadIdx.x >> 6);
    float acc0 = x[(size_t)row * 74 + lane];
    float acc1 = pn[(size_t)row * 64 + lane];
    #pragma unroll
    for (int j = 0; j < 8; ++j) {
        int nb   = idx[row * 8 + j];
        float sg = sgn[row * 8 + j];
        acc0 += sg * x[(size_t)nb * 74 + lane];
        acc1 += sg * pn[(size_t)nb * 64 + lane];
    }
    agg[(size_t)row * 128 + lane]      = acc0;
    agg[(size_t)row * 128 + 64 + lane] = acc1;
}

// ---- generic aggregation for F=64 activations ----
__global__ __launch_bounds__(256) void k_gather2(
    const float* __restrict__ h, const int* __restrict__ idx,
    const float* __restrict__ sgn, float* __restrict__ agg)
{
    int lane = threadIdx.x & 63;
    int row  = blockIdx.x * 4 + (threadIdx.x >> 6);
    float acc = h[(size_t)row * 64 + lane];
    #pragma unroll
    for (int j = 0; j < 8; ++j) {
        int nb   = idx[row * 8 + j];
        float sg = sgn[row * 8 + j];
        acc += sg * h[(size_t)nb * 64 + lane];
    }
    agg[(size_t)row * 64 + lane] = acc;
}

// ---- layer 1 GEMM: [x | pn | agg128] . W[256][64], thread = (row, 4 cols) ----
__global__ __launch_bounds__(256) void k_gemm1(
    const float* __restrict__ x, const float* __restrict__ pn,
    const float* __restrict__ agg,
    const float* __restrict__ wn, const float* __restrict__ we,
    const float* __restrict__ bn, const float* __restrict__ be,
    float* __restrict__ out)
{
    int r_l = threadIdx.x >> 2, cg = threadIdx.x & 3;
    int row = blockIdx.x * 64 + r_l;
    int c0  = blockIdx.y * 16 + cg * 4;
    bool isnode = blockIdx.x < 64;             // 64-row blocks: block-uniform
    const float* W = isnode ? wn : we;
    const float* B = isnode ? bn : be;
    float acc[4] = {B[c0], B[c0 + 1], B[c0 + 2], B[c0 + 3]};

    const float2* x2 = (const float2*)(x + (size_t)row * 74);   // 74 floats: float2-aligned
    #pragma unroll
    for (int kg = 0; kg < 32; ++kg) {
        float2 v = x2[kg];
        float4 wv0 = *(const float4*)&W[(kg * 2) * 64 + c0];
        float4 wv1 = *(const float4*)&W[(kg * 2 + 1) * 64 + c0];
        acc[0] += v.x * wv0.x + v.y * wv1.x;
        acc[1] += v.x * wv0.y + v.y * wv1.y;
        acc[2] += v.x * wv0.z + v.y * wv1.z;
        acc[3] += v.x * wv0.w + v.y * wv1.w;
    }
    const float4* p4 = (const float4*)(pn + (size_t)row * 64);
    #pragma unroll
    for (int kg = 0; kg < 16; ++kg) {
        float4 v = p4[kg];
        const float* vv = &v.x;
        #pragma unroll
        for (int kk = 0; kk < 4; ++kk) {
            float4 wv = *(const float4*)&W[(64 + kg * 4 + kk) * 64 + c0];
            acc[0] += vv[kk] * wv.x; acc[1] += vv[kk] * wv.y;
            acc[2] += vv[kk] * wv.z; acc[3] += vv[kk] * wv.w;
        }
    }
    const float4* a4 = (const float4*)(agg + (size_t)row * 128);
    #pragma unroll
    for (int kg = 0; kg < 32; ++kg) {
        float4 v = a4[kg];
        const float* vv = &v.x;
        #pragma unroll
        for (int kk = 0; kk < 4; ++kk) {
            float4 wv = *(const float4*)&W[(128 + kg * 4 + kk) * 64 + c0];
            acc[0] += vv[kk] * wv.x; acc[1] += vv[kk] * wv.y;
            acc[2] += vv[kk] * wv.z; acc[3] += vv[kk] * wv.w;
        }
    }
    float4 o;
    o.x = fmaxf(acc[0], 0.f); o.y = fmaxf(acc[1], 0.f);
    o.z = fmaxf(acc[2], 0.f); o.w = fmaxf(acc[3], 0.f);
    *(float4*)&out[(size_t)row * 64 + c0] = o;
}

// ---- layer 2 GEMM: [h1 | agg64] . W[128][64] ----
__global__ __launch_bounds__(256) void k_gemm2(
    const float* __restrict__ h, const float* __restrict__ agg,
    const float* __restrict__ wn, const float* __restrict__ we,
    const float* __restrict__ bn, const float* __restrict__ be,
    float* __restrict__ out)
{
    int r_l = threadIdx.x >> 2, cg = threadIdx.x & 3;
    int row = blockIdx.x * 64 + r_l;
    int c0  = blockIdx.y * 16 + cg * 4;
    bool isnode = blockIdx.x < 64;
    const float* W = isnode ? wn : we;
    const float* B = isnode ? bn : be;
    float acc[4] = {B[c0], B[c0 + 1], B[c0 + 2], B[c0 + 3]};

    const float4* h4 = (const float4*)(h + (size_t)row * 64);
    const float4* a4 = (const float4*)(agg + (size_t)row * 64);
    #pragma unroll
    for (int kg = 0; kg < 16; ++kg) {
        float4 v = h4[kg];
        const float* vv = &v.x;
        #pragma unroll
        for (int kk = 0; kk < 4; ++kk) {
            float4 wv = *(const float4*)&W[(kg * 4 + kk) * 64 + c0];
            acc[0] += vv[kk] * wv.x; acc[1] += vv[kk] * wv.y;
            acc[2] += vv[kk] * wv.z; acc[3] += vv[kk] * wv.w;
        }
    }
    #pragma unroll
    for (int kg = 0; kg < 16; ++kg) {
        float4 v = a4[kg];
        const float* vv = &v.x;
        #pragma unroll
        for (int kk = 0; kk < 4; ++kk) {
            float4 wv = *(const float4*)&W[(64 + kg * 4 + kk) * 64 + c0];
            acc[0] += vv[kk] * wv.x; acc[1] += vv[kk] * wv.y;
            acc[2] += vv[kk] * wv.z; acc[3] += vv[kk] * wv.w;
        }
    }
    float4 o;
    o.x = fmaxf(acc[0], 0.f); o.y = fmaxf(acc[1], 0.f);
    o.z = fmaxf(acc[2], 0.f); o.w = fmaxf(acc[3], 0.f);
    *(float4*)&out[(size_t)row * 64 + c0] = o;
}

// ---- layer 3 fused: gather + 128->1 dot + sigmoid, wave per row ----
__global__ __launch_bounds__(256) void k_gc3(
    const float* __restrict__ h2, const int* __restrict__ idx,
    const float* __restrict__ sgn,
    const float* __restrict__ wn, const float* __restrict__ we,
    const float* __restrict__ bn, const float* __restrict__ be,
    float* __restrict__ out)
{
    int lane = threadIdx.x & 63;
    int row  = blockIdx.x * 4 + (threadIdx.x >> 6);
    float own = h2[(size_t)row * 64 + lane];
    float agg = own;
    #pragma unroll
    for (int j = 0; j < 8; ++j) {
        int nb   = idx[row * 8 + j];
        float sg = sgn[row * 8 + j];
        agg += sg * h2[(size_t)nb * 64 + lane];
    }
    bool isnode = row < NDET;                  // wave-uniform (rows per wave aligned)
    const float* w = isnode ? wn : we;
    float bias = isnode ? bn[0] : be[0];
    float acc = own * w[lane] + agg * w[64 + lane];
    #pragma unroll
    for (int off = 32; off > 0; off >>= 1)
        acc += __shfl_xor(acc, off, 64);
    if (lane == 0)
        out[row] = 1.f / (1.f + expf(-(acc + bias)));
}

extern "C" void kernel_launch(void* const* d_in, const int* in_sizes, int n_in,
                              void* d_out, int out_size, void* d_ws, size_t ws_size,
                              hipStream_t stream)
{
    const float* x     = (const float*)d_in[0];
    const float* nodeA = (const float*)d_in[1];
    const float* edgeA = (const float*)d_in[2];
    const float* pw1 = (const float*)d_in[3];  const float* pb1 = (const float*)d_in[4];
    const float* pg1 = (const float*)d_in[5];  const float* pe1 = (const float*)d_in[6];
    const float* pm1 = (const float*)d_in[7];  const float* pv1 = (const float*)d_in[8];
    const float* pw2 = (const float*)d_in[9];  const float* pb2 = (const float*)d_in[10];
    const float* pg2 = (const float*)d_in[11]; const float* pe2 = (const float*)d_in[12];
    const float* pm2 = (const float*)d_in[13]; const float* pv2 = (const float*)d_in[14];
    const float* pw3 = (const float*)d_in[15]; const float* pb3 = (const float*)d_in[16];
    const float* pg3 = (const float*)d_in[17]; const float* pe3 = (const float*)d_in[18];
    const float* pm3 = (const float*)d_in[19]; const float* pv3 = (const float*)d_in[20];
    const float* g1wn = (const float*)d_in[21]; const float* g1we = (const float*)d_in[22];
    const float* g1bn = (const float*)d_in[23]; const float* g1be = (const float*)d_in[24];
    const float* g2wn = (const float*)d_in[25]; const float* g2we = (const float*)d_in[26];
    const float* g2bn = (const float*)d_in[27]; const float* g2be = (const float*)d_in[28];
    const float* g3wn = (const float*)d_in[29]; const float* g3we = (const float*)d_in[30];
    const float* g3bn = (const float*)d_in[31]; const float* g3be = (const float*)d_in[32];

    float* ws  = (float*)d_ws;
    int*   idx = (int*)ws;
    float* sgn = ws + OFF_SGN;
    float* pn  = ws + OFF_PN;
    float* agg = ws + OFF_AGG;
    float* h1  = ws + OFF_H1;
    float* h2  = ws + OFF_H2;
    float* out = (float*)d_out;

    k_extract<<<NROWS, 256, 0, stream>>>(nodeA, edgeA, idx, sgn);
    k_pointnet<<<dim3(128, 4), 256, 0, stream>>>(x,
        pw1, pb1, pg1, pe1, pm1, pv1,
        pw2, pb2, pg2, pe2, pm2, pv2,
        pw3, pb3, pg3, pe3, pm3, pv3, pn);
    k_gather1<<<2048, 256, 0, stream>>>(x, pn, idx, sgn, agg);
    k_gemm1<<<dim3(128, 4), 256, 0, stream>>>(x, pn, agg, g1wn, g1we, g1bn, g1be, h1);
    k_gather2<<<2048, 256, 0, stream>>>(h1, idx, sgn, agg);
    k_gemm2<<<dim3(128, 4), 256, 0, stream>>>(h1, agg, g2wn, g2we, g2bn, g2be, h2);
    k_gc3<<<2048, 256, 0, stream>>>(h2, idx, sgn, g3wn, g3we, g3bn, g3be, out);
}

// Round 4
// 552.835 us; speedup vs baseline: 1.9283x; 1.7630x over previous
//
#include <hip/hip_runtime.h>
#include <math.h>

#define NROWS 8192
#define NDET  4096

// ---------------- workspace layout (float element offsets) ----------------
static constexpr int OFF_SGN = 65536;
static constexpr int OFF_PN  = 131072;
static constexpr int OFF_AGG = 655360;
static constexpr int OFF_H1  = 1703936;
static constexpr int OFF_H2  = 2228224;

// ---- sparse extraction: one block per row, scan the half that can hold neighbors ----
__global__ __launch_bounds__(256) void k_extract(
    const float* __restrict__ nodeA, const float* __restrict__ edgeA,
    int* __restrict__ idx, float* __restrict__ sgn)
{
    int row = blockIdx.x, t = threadIdx.x;
    const float* src; int col0;
    if (row < NDET) { src = nodeA + (size_t)row * NROWS + NDET; col0 = NDET; }
    else            { src = edgeA + (size_t)row * NROWS;        col0 = 0;    }
    __shared__ int scnt;
    if (t == 0) scnt = 0;
    __syncthreads();
    const float4* s4 = (const float4*)src;
    #pragma unroll
    for (int it = 0; it < 4; ++it) {
        float4 v = s4[t + it * 256];
        int cb = col0 + (t + it * 256) * 4;
        if (v.x != 0.f) { int p = atomicAdd(&scnt, 1); idx[row * 8 + p] = cb;     sgn[row * 8 + p] = v.x; }
        if (v.y != 0.f) { int p = atomicAdd(&scnt, 1); idx[row * 8 + p] = cb + 1; sgn[row * 8 + p] = v.y; }
        if (v.z != 0.f) { int p = atomicAdd(&scnt, 1); idx[row * 8 + p] = cb + 2; sgn[row * 8 + p] = v.z; }
        if (v.w != 0.f) { int p = atomicAdd(&scnt, 1); idx[row * 8 + p] = cb + 3; sgn[row * 8 + p] = v.w; }
    }
    __syncthreads();
    for (int p = scnt + t; p < 8; p += 256) { idx[row * 8 + p] = 0; sgn[row * 8 + p] = 0.f; }
}

// ---- pointnet, wave-per-row, lane = output channel. NO per-thread arrays ->
// spill-proof (r2/r3: per-thread h1[16]/h2[32] spilled to scratch, 1.2-1.4 GB HBM traffic).
// Cross-channel dependencies flow through __shfl (wave-synchronous, no barriers).
__global__ __launch_bounds__(256) void k_pointnet(
    const float* __restrict__ x,
    const float* __restrict__ w1, const float* __restrict__ b1,
    const float* __restrict__ g1, const float* __restrict__ be1,
    const float* __restrict__ m1, const float* __restrict__ v1,
    const float* __restrict__ w2, const float* __restrict__ b2,
    const float* __restrict__ g2, const float* __restrict__ be2,
    const float* __restrict__ m2, const float* __restrict__ v2,
    const float* __restrict__ w3, const float* __restrict__ b3,
    const float* __restrict__ g3, const float* __restrict__ be3,
    const float* __restrict__ m3, const float* __restrict__ v3,
    float* __restrict__ pn)
{
    // folded weights: fw1[3][16]@0, fb1@48, fw2[16][32]@64, fb2@576, fw3[32][64]@608, fb3@2656
    __shared__ float fw[2720];
    int t = threadIdx.x;
    for (int i = t; i < 48; i += 256)  { int d = i & 15; fw[i]       = w1[i] * g1[d] * rsqrtf(v1[d] + 1e-5f); }
    for (int i = t; i < 16; i += 256)  {                 fw[48 + i]  = (b1[i] - m1[i]) * g1[i] * rsqrtf(v1[i] + 1e-5f) + be1[i]; }
    for (int i = t; i < 512; i += 256) { int d = i & 31; fw[64 + i]  = w2[i] * g2[d] * rsqrtf(v2[d] + 1e-5f); }
    for (int i = t; i < 32; i += 256)  {                 fw[576 + i] = (b2[i] - m2[i]) * g2[i] * rsqrtf(v2[i] + 1e-5f) + be2[i]; }
    for (int i = t; i < 2048; i += 256){ int d = i & 63; fw[608 + i] = w3[i] * g3[d] * rsqrtf(v3[d] + 1e-5f); }
    for (int i = t; i < 64; i += 256)  {                 fw[2656 + i]= (b3[i] - m3[i]) * g3[i] * rsqrtf(v3[i] + 1e-5f) + be3[i]; }
    __syncthreads();

    int lane = t & 63;
    int wv   = t >> 6;                               // 4 waves/block
    int l15  = lane & 15, l31 = lane & 31;
    int rowbase = (blockIdx.x * 4 + wv) * 4;         // grid 512 blocks, 4 rows/wave

    for (int r = rowbase; r < rowbase + 4; ++r) {
        float val  = (lane < 10) ? x[(size_t)r * 74 + 64 + lane] : 0.f;
        float vmax = -3.0e38f;
        #pragma unroll
        for (int p = 0; p < 5; ++p) {
            float a0 = __shfl(val, p, 64);
            float a1 = __shfl(val, p + 5, 64);
            // h1 channel = lane (valid on lanes 0..15)
            float h1v = fmaxf(0.f, a0 * fw[l15] + a1 * fw[16 + l15] + fw[48 + l15]);
            // h2 channel = lane (valid on lanes 0..31)
            float s2 = fw[576 + l31];
            #pragma unroll
            for (int d = 0; d < 16; ++d)
                s2 += __shfl(h1v, d, 64) * fw[64 + d * 32 + l31];
            float h2v = fmaxf(0.f, s2);
            // h3 channel = lane (all 64 lanes)
            float s3 = fw[2656 + lane];
            #pragma unroll
            for (int e = 0; e < 32; ++e)
                s3 += __shfl(h2v, e, 64) * fw[608 + e * 64 + lane];
            vmax = fmaxf(vmax, s3);
        }
        pn[(size_t)r * 64 + lane] = vmax;            // coalesced 256 B/wave
    }
}

// ---- layer-1 aggregation: wave per row, full-line coalesced neighbor reads ----
__global__ __launch_bounds__(256) void k_gather1(
    const float* __restrict__ x, const float* __restrict__ pn,
    const int* __restrict__ idx, const float* __restrict__ sgn,
    float* __restrict__ agg)
{
    int lane = threadIdx.x & 63;
    int row  = blockIdx.x * 4 + (threadIdx.x >> 6);
    float acc0 = x[(size_t)row * 74 + lane];
    float acc1 = pn[(size_t)row * 64 + lane];
    #pragma unroll
    for (int j = 0; j < 8; ++j) {
        int nb   = idx[row * 8 + j];
        float sg = sgn[row * 8 + j];
        acc0 += sg * x[(size_t)nb * 74 + lane];
        acc1 += sg * pn[(size_t)nb * 64 + lane];
    }
    agg[(size_t)row * 128 + lane]      = acc0;
    agg[(size_t)row * 128 + 64 + lane] = acc1;
}

// ---- generic aggregation for F=64 activations ----
__global__ __launch_bounds__(256) void k_gather2(
    const float* __restrict__ h, const int* __restrict__ idx,
    const float* __restrict__ sgn, float* __restrict__ agg)
{
    int lane = threadIdx.x & 63;
    int row  = blockIdx.x * 4 + (threadIdx.x >> 6);
    float acc = h[(size_t)row * 64 + lane];
    #pragma unroll
    for (int j = 0; j < 8; ++j) {
        int nb   = idx[row * 8 + j];
        float sg = sgn[row * 8 + j];
        acc += sg * h[(size_t)nb * 64 + lane];
    }
    agg[(size_t)row * 64 + lane] = acc;
}

// ---- layer 1 GEMM: [x | pn | agg128] . W[256][64], thread = (row, 4 cols) ----
__global__ __launch_bounds__(256) void k_gemm1(
    const float* __restrict__ x, const float* __restrict__ pn,
    const float* __restrict__ agg,
    const float* __restrict__ wn, const float* __restrict__ we,
    const float* __restrict__ bn, const float* __restrict__ be,
    float* __restrict__ out)
{
    int r_l = threadIdx.x >> 2, cg = threadIdx.x & 3;
    int row = blockIdx.x * 64 + r_l;
    int c0  = blockIdx.y * 16 + cg * 4;
    bool isnode = blockIdx.x < 64;             // 64-row blocks: block-uniform
    const float* W = isnode ? wn : we;
    const float* B = isnode ? bn : be;
    float acc[4] = {B[c0], B[c0 + 1], B[c0 + 2], B[c0 + 3]};

    const float2* x2 = (const float2*)(x + (size_t)row * 74);   // 74 floats: float2-aligned
    #pragma unroll
    for (int kg = 0; kg < 32; ++kg) {
        float2 v = x2[kg];
        float4 wv0 = *(const float4*)&W[(kg * 2) * 64 + c0];
        float4 wv1 = *(const float4*)&W[(kg * 2 + 1) * 64 + c0];
        acc[0] += v.x * wv0.x + v.y * wv1.x;
        acc[1] += v.x * wv0.y + v.y * wv1.y;
        acc[2] += v.x * wv0.z + v.y * wv1.z;
        acc[3] += v.x * wv0.w + v.y * wv1.w;
    }
    const float4* p4 = (const float4*)(pn + (size_t)row * 64);
    #pragma unroll
    for (int kg = 0; kg < 16; ++kg) {
        float4 v = p4[kg];
        const float* vv = &v.x;
        #pragma unroll
        for (int kk = 0; kk < 4; ++kk) {
            float4 wv = *(const float4*)&W[(64 + kg * 4 + kk) * 64 + c0];
            acc[0] += vv[kk] * wv.x; acc[1] += vv[kk] * wv.y;
            acc[2] += vv[kk] * wv.z; acc[3] += vv[kk] * wv.w;
        }
    }
    const float4* a4 = (const float4*)(agg + (size_t)row * 128);
    #pragma unroll
    for (int kg = 0; kg < 32; ++kg) {
        float4 v = a4[kg];
        const float* vv = &v.x;
        #pragma unroll
        for (int kk = 0; kk < 4; ++kk) {
            float4 wv = *(const float4*)&W[(128 + kg * 4 + kk) * 64 + c0];
            acc[0] += vv[kk] * wv.x; acc[1] += vv[kk] * wv.y;
            acc[2] += vv[kk] * wv.z; acc[3] += vv[kk] * wv.w;
        }
    }
    float4 o;
    o.x = fmaxf(acc[0], 0.f); o.y = fmaxf(acc[1], 0.f);
    o.z = fmaxf(acc[2], 0.f); o.w = fmaxf(acc[3], 0.f);
    *(float4*)&out[(size_t)row * 64 + c0] = o;
}

// ---- layer 2 GEMM: [h1 | agg64] . W[128][64] ----
__global__ __launch_bounds__(256) void k_gemm2(
    const float* __restrict__ h, const float* __restrict__ agg,
    const float* __restrict__ wn, const float* __restrict__ we,
    const float* __restrict__ bn, const float* __restrict__ be,
    float* __restrict__ out)
{
    int r_l = threadIdx.x >> 2, cg = threadIdx.x & 3;
    int row = blockIdx.x * 64 + r_l;
    int c0  = blockIdx.y * 16 + cg * 4;
    bool isnode = blockIdx.x < 64;
    const float* W = isnode ? wn : we;
    const float* B = isnode ? bn : be;
    float acc[4] = {B[c0], B[c0 + 1], B[c0 + 2], B[c0 + 3]};

    const float4* h4 = (const float4*)(h + (size_t)row * 64);
    const float4* a4 = (const float4*)(agg + (size_t)row * 64);
    #pragma unroll
    for (int kg = 0; kg < 16; ++kg) {
        float4 v = h4[kg];
        const float* vv = &v.x;
        #pragma unroll
        for (int kk = 0; kk < 4; ++kk) {
            float4 wv = *(const float4*)&W[(kg * 4 + kk) * 64 + c0];
            acc[0] += vv[kk] * wv.x; acc[1] += vv[kk] * wv.y;
            acc[2] += vv[kk] * wv.z; acc[3] += vv[kk] * wv.w;
        }
    }
    #pragma unroll
    for (int kg = 0; kg < 16; ++kg) {
        float4 v = a4[kg];
        const float* vv = &v.x;
        #pragma unroll
        for (int kk = 0; kk < 4; ++kk) {
            float4 wv = *(const float4*)&W[(64 + kg * 4 + kk) * 64 + c0];
            acc[0] += vv[kk] * wv.x; acc[1] += vv[kk] * wv.y;
            acc[2] += vv[kk] * wv.z; acc[3] += vv[kk] * wv.w;
        }
    }
    float4 o;
    o.x = fmaxf(acc[0], 0.f); o.y = fmaxf(acc[1], 0.f);
    o.z = fmaxf(acc[2], 0.f); o.w = fmaxf(acc[3], 0.f);
    *(float4*)&out[(size_t)row * 64 + c0] = o;
}

// ---- layer 3 fused: gather + 128->1 dot + sigmoid, wave per row ----
__global__ __launch_bounds__(256) void k_gc3(
    const float* __restrict__ h2, const int* __restrict__ idx,
    const float* __restrict__ sgn,
    const float* __restrict__ wn, const float* __restrict__ we,
    const float* __restrict__ bn, const float* __restrict__ be,
    float* __restrict__ out)
{
    int lane = threadIdx.x & 63;
    int row  = blockIdx.x * 4 + (threadIdx.x >> 6);
    float own = h2[(size_t)row * 64 + lane];
    float agg = own;
    #pragma unroll
    for (int j = 0; j < 8; ++j) {
        int nb   = idx[row * 8 + j];
        float sg = sgn[row * 8 + j];
        agg += sg * h2[(size_t)nb * 64 + lane];
    }
    bool isnode = row < NDET;                  // wave-uniform (rows per wave aligned)
    const float* w = isnode ? wn : we;
    float bias = isnode ? bn[0] : be[0];
    float acc = own * w[lane] + agg * w[64 + lane];
    #pragma unroll
    for (int off = 32; off > 0; off >>= 1)
        acc += __shfl_xor(acc, off, 64);
    if (lane == 0)
        out[row] = 1.f / (1.f + expf(-(acc + bias)));
}

extern "C" void kernel_launch(void* const* d_in, const int* in_sizes, int n_in,
                              void* d_out, int out_size, void* d_ws, size_t ws_size,
                              hipStream_t stream)
{
    const float* x     = (const float*)d_in[0];
    const float* nodeA = (const float*)d_in[1];
    const float* edgeA = (const float*)d_in[2];
    const float* pw1 = (const float*)d_in[3];  const float* pb1 = (const float*)d_in[4];
    const float* pg1 = (const float*)d_in[5];  const float* pe1 = (const float*)d_in[6];
    const float* pm1 = (const float*)d_in[7];  const float* pv1 = (const float*)d_in[8];
    const float* pw2 = (const float*)d_in[9];  const float* pb2 = (const float*)d_in[10];
    const float* pg2 = (const float*)d_in[11]; const float* pe2 = (const float*)d_in[12];
    const float* pm2 = (const float*)d_in[13]; const float* pv2 = (const float*)d_in[14];
    const float* pw3 = (const float*)d_in[15]; const float* pb3 = (const float*)d_in[16];
    const float* pg3 = (const float*)d_in[17]; const float* pe3 = (const float*)d_in[18];
    const float* pm3 = (const float*)d_in[19]; const float* pv3 = (const float*)d_in[20];
    const float* g1wn = (const float*)d_in[21]; const float* g1we = (const float*)d_in[22];
    const float* g1bn = (const float*)d_in[23]; const float* g1be = (const float*)d_in[24];
    const float* g2wn = (const float*)d_in[25]; const float* g2we = (const float*)d_in[26];
    const float* g2bn = (const float*)d_in[27]; const float* g2be = (const float*)d_in[28];
    const float* g3wn = (const float*)d_in[29]; const float* g3we = (const float*)d_in[30];
    const float* g3bn = (const float*)d_in[31]; const float* g3be = (const float*)d_in[32];

    float* ws  = (float*)d_ws;
    int*   idx = (int*)ws;
    float* sgn = ws + OFF_SGN;
    float* pn  = ws + OFF_PN;
    float* agg = ws + OFF_AGG;
    float* h1  = ws + OFF_H1;
    float* h2  = ws + OFF_H2;
    float* out = (float*)d_out;

    k_extract<<<NROWS, 256, 0, stream>>>(nodeA, edgeA, idx, sgn);
    k_pointnet<<<512, 256, 0, stream>>>(x,
        pw1, pb1, pg1, pe1, pm1, pv1,
        pw2, pb2, pg2, pe2, pm2, pv2,
        pw3, pb3, pg3, pe3, pm3, pv3, pn);
    k_gather1<<<2048, 256, 0, stream>>>(x, pn, idx, sgn, agg);
    k_gemm1<<<dim3(128, 4), 256, 0, stream>>>(x, pn, agg, g1wn, g1we, g1bn, g1be, h1);
    k_gather2<<<2048, 256, 0, stream>>>(h1, idx, sgn, agg);
    k_gemm2<<<dim3(128, 4), 256, 0, stream>>>(h1, agg, g2wn, g2we, g2bn, g2be, h2);
    k_gc3<<<2048, 256, 0, stream>>>(h2, idx, sgn, g3wn, g3we, g3bn, g3be, out);
}